// Round 8
// baseline (110.750 us; speedup 1.0000x reference)
//
#include <hip/hip_runtime.h>
#include <cstdint>

// ---------------------------------------------------------------------------
// QuantumBranch, R11: high-occupancy, exchange-free, store-spread main.
// R8/R10 post-mortem: HBM (18%) and VALU (12%) duty cycles anti-correlated —
// waves compute then burst stores; 2-4 waves/SIMD can't overlap the phases;
// 64MB at the measured 1.4TB/s = the observed ~46us. The fill proves 6TB/s
// at 8 waves/CU with store-only waves. R11 attacks the three never-tested
// structural properties at once:
//  (1) i-outer matvec (j-inner, same j-ascending FMA association) -> live
//      state m[16]+z[4]+misc ~= 40 VGPR, no launch_bounds cap needed.
//  (2) V rows row-major in ws (setup writes a 2nd transposed copy), read
//      via address_space(4) s_load (R3-proven). Zero DS ops in main.
//  (3) exchange-free stores: thread stores its OWN sample's 64 outputs as
//      16 x float4 into its 256B slot, interleaved with the per-k FMAs.
//      Wave covers every byte of the 16KB span in 16 instructions -> L2
//      assembles full lines. No LDS, no barrier, no end-of-life burst.
//  Grid 2048 x 128 = 8 blocks/CU, 16 waves/CU (2-4x prior residency).
// Per-output FMA order verbatim R9 -> absmax stays exactly 0.015625.
//
// Math (verified R1-R10): circuit collapses to V = U*diag((-i)^popc),
// z_w = sum_i +/- (r_i^2+s_i^2), r=Re(V)m, s=Im(V)m, m = product-state
// magnitudes from tanh(x)*pi/2. LayerNorm collapses to a 4x4 quadratic
// form: out[b,k] = inv_b*(A[k].q_b + B0[k]) + beta[k].
// ---------------------------------------------------------------------------

#define CONST_AS __attribute__((address_space(4)))
template <typename T>
__device__ inline const CONST_AS T* as_const4(const T* p) {
    return (const CONST_AS T*)(uintptr_t)p;
}

// ws float offsets (global workspace, 1376 floats = 5.5KB)
#define WS_VRT 0     // 256: Re(V)^T  [col*16+row]   (kept for reference)
#define WS_VIT 256   // 256: Im(V)^T
#define WS_A   512   // 256: (W-colmean)*gamma  [k*4+w]
#define WS_B0  768   // 64:  (b-bmean)*gamma
#define WS_G   832   // 16:  G[4][4]
#define WS_g   848   // 4
#define WS_C0  852   // 1
#define WS_VR2 864   // 256: Re(V)^T row-major [row*16+col] (i-outer reads)
#define WS_VI2 1120  // 256: Im(V)^T row-major

// One wave, no barriers. lane = row*4 + cg; lane holds U[row][4cg..4cg+3].
__global__ __launch_bounds__(64) void qb_setup(const float* __restrict__ wts,
                                               const float* __restrict__ W,
                                               const float* __restrict__ bias,
                                               const float* __restrict__ gamma,
                                               float* __restrict__ ws) {
    const int lane = threadIdx.x;
    const int row  = lane >> 2;
    const int cg   = lane & 3;

    float ur[4], ui[4];   // U[row][4cg+c]
    #pragma unroll
    for (int c = 0; c < 4; ++c) {
        ur[c] = (row == 4*cg + c) ? 1.f : 0.f;
        ui[c] = 0.f;
    }

    #pragma unroll
    for (int l = 0; l < 2; ++l) {
        #pragma unroll
        for (int w = 0; w < 4; ++w) {
            const float ph = wts[l*12 + w*3 + 0];
            const float th = wts[l*12 + w*3 + 1];
            const float om = wts[l*12 + w*3 + 2];
            float st, ct; __sincosf(0.5f*th, &st, &ct);
            float sp, cp; __sincosf(0.5f*(ph+om), &sp, &cp);
            float sm, cm; __sincosf(0.5f*(ph-om), &sm, &cm);
            const float a00r =  cp*ct, a00i = -sp*ct;
            const float a01r = -cm*st, a01i = -sm*st;
            const float a10r =  cm*st, a10i = -sm*st;
            const float a11r =  cp*ct, a11i =  sp*ct;
            const int m8 = 8 >> w;
            const int xm = m8 << 2;            // lane xor mask for row^m8
            const bool hi = (row & m8) != 0;
            #pragma unroll
            for (int c = 0; c < 4; ++c) {
                const float pr = __shfl_xor(ur[c], xm, 64);
                const float pi = __shfl_xor(ui[c], xm, 64);
                float nr, ni;
                if (!hi) {
                    nr = a00r*ur[c] - a00i*ui[c] + a01r*pr - a01i*pi;
                    ni = a00r*ui[c] + a00i*ur[c] + a01r*pi + a01i*pr;
                } else {
                    nr = a11r*ur[c] - a11i*ui[c] + a10r*pr - a10i*pi;
                    ni = a11r*ui[c] + a11i*ur[c] + a10r*pi + a10i*pr;
                }
                ur[c] = nr; ui[c] = ni;
            }
        }
        const int rr = (l == 0) ? 1 : 2;
        #pragma unroll
        for (int w = 0; w < 4; ++w) {
            const int cmk = 8 >> w;
            const int tmk = 8 >> ((w + rr) & 3);
            const int src = (row & cmk) ? (row ^ tmk) : row;
            const int srcLane = src*4 + cg;
            #pragma unroll
            for (int c = 0; c < 4; ++c) {
                ur[c] = __shfl(ur[c], srcLane, 64);
                ui[c] = __shfl(ui[c], srcLane, 64);
            }
        }
    }

    // V = U * diag((-i)^popc); store both layouts
    #pragma unroll
    for (int c = 0; c < 4; ++c) {
        const int col = 4*cg + c;
        const int p = __popc(col) & 3;
        float vr, vi;
        if (p == 0)      { vr =  ur[c]; vi =  ui[c]; }
        else if (p == 1) { vr =  ui[c]; vi = -ur[c]; }
        else if (p == 2) { vr = -ur[c]; vi = -ui[c]; }
        else             { vr = -ui[c]; vi =  ur[c]; }
        ws[WS_VRT + col*16 + row] = vr;
        ws[WS_VIT + col*16 + row] = vi;
        ws[WS_VR2 + row*16 + col] = vr;   // row-major for i-outer matvec
        ws[WS_VI2 + row*16 + col] = vi;
    }

    // Projection / layernorm constants: lane k
    {
        const int k = lane;
        float w0 = W[k*4+0], w1 = W[k*4+1], w2 = W[k*4+2], w3 = W[k*4+3];
        float bk = bias[k];
        auto wsum = [](float v) {
            #pragma unroll
            for (int o = 32; o; o >>= 1) v += __shfl_xor(v, o, 64);
            return v;
        };
        const float inv64 = 1.f/64.f;
        const float m0 = wsum(w0)*inv64, m1 = wsum(w1)*inv64;
        const float m2 = wsum(w2)*inv64, m3 = wsum(w3)*inv64;
        const float bm = wsum(bk)*inv64;
        float cc[4] = {w0-m0, w1-m1, w2-m2, w3-m3};
        const float bc = bk - bm;
        const float gk = gamma[k];
        #pragma unroll
        for (int w = 0; w < 4; ++w) ws[WS_A + k*4 + w] = cc[w]*gk;
        ws[WS_B0 + k] = bc*gk;
        #pragma unroll
        for (int a = 0; a < 4; ++a)
            #pragma unroll
            for (int b2 = a; b2 < 4; ++b2) {
                const float s = wsum(cc[a]*cc[b2])*inv64;
                if (k == 0) {
                    ws[WS_G + a*4 + b2] = s;
                    ws[WS_G + b2*4 + a] = s;
                }
            }
        #pragma unroll
        for (int a = 0; a < 4; ++a) {
            const float s = wsum(bc*cc[a])*inv64;
            if (k == 0) ws[WS_g + a] = s;
        }
        {
            const float s = wsum(bc*bc)*inv64;
            if (k == 0) ws[WS_C0] = s;
        }
    }
}

// 2048 blocks x 128 threads, 1 sample/thread. No LDS, no barriers, no
// exchange. Low VGPR (i-outer matvec) -> high occupancy. Stores spread
// across the k-loop, each thread filling its own 256B slot.
__global__ __launch_bounds__(128) void qb_main(const float* __restrict__ x,
                                               const float* __restrict__ beta,
                                               const float* __restrict__ ws,
                                               float* __restrict__ out) {
    const int sample = blockIdx.x * 128 + threadIdx.x;
    const float4 xv = ((const float4*)x)[sample];
    const CONST_AS float* V = as_const4(ws);
    const CONST_AS float* Bt = as_const4(beta);

    // ---- product-state magnitudes m[16] ----
    float m[16];
    {
        const float xa[4] = {xv.x, xv.y, xv.z, xv.w};
        float c4[4], s4[4];
        #pragma unroll
        for (int w = 0; w < 4; ++w) {
            const float h = tanhf(xa[w]) * 1.5707963267948966f;
            __sincosf(h, &s4[w], &c4[w]);
        }
        const float e01[4] = {c4[0]*c4[1], c4[0]*s4[1], s4[0]*c4[1], s4[0]*s4[1]};
        const float e23[4] = {c4[2]*c4[3], c4[2]*s4[3], s4[2]*c4[3], s4[2]*s4[3]};
        #pragma unroll
        for (int j = 0; j < 16; ++j) m[j] = e01[j>>2]*e23[j&3];
    }

    // ---- i-outer matvec + immediate z accumulation ----
    // r_i folds j ascending (identical association to the j-outer version);
    // z0..z3 accumulate p_i in i-ascending order (identical to before).
    float z0 = 0.f, z1 = 0.f, z2 = 0.f, z3 = 0.f;
    #pragma unroll
    for (int i = 0; i < 16; ++i) {
        float ri = 0.f, ti = 0.f;
        #pragma unroll
        for (int j = 0; j < 16; ++j) {
            ri = fmaf(V[WS_VR2 + i*16 + j], m[j], ri);
            ti = fmaf(V[WS_VI2 + i*16 + j], m[j], ti);
        }
        const float p = ri*ri + ti*ti;
        z0 += (i & 8) ? -p : p;
        z1 += (i & 4) ? -p : p;
        z2 += (i & 2) ? -p : p;
        z3 += (i & 1) ? -p : p;
    }

    // ---- finish: softmax -> var -> inv ----
    const float mx = fmaxf(fmaxf(z0, z1), fmaxf(z2, z3));
    const float e0 = __expf(z0-mx), e1 = __expf(z1-mx);
    const float e2 = __expf(z2-mx), e3 = __expf(z3-mx);
    const float rs = 1.f / (e0+e1+e2+e3);
    const float qx = e0*rs, qy = e1*rs, qz = e2*rs, qw = e3*rs;

    float var = V[WS_C0];
    {
        const float qa[4] = {qx, qy, qz, qw};
        #pragma unroll
        for (int a = 0; a < 4; ++a) {
            float t = 2.f * V[WS_g + a];
            #pragma unroll
            for (int b2 = 0; b2 < 4; ++b2) t = fmaf(V[WS_G + a*4 + b2], qa[b2], t);
            var = fmaf(qa[a], t, var);
        }
    }
    const float inv = rsqrtf(var + 1e-5f);

    // ---- exchange-free store: thread fills its own 256B slot ----
    // FMA association per output element verbatim R9's store phase.
    float* slot = out + (size_t)sample * 64;
    #pragma unroll
    for (int kb = 0; kb < 16; ++kb) {
        float4 o;
        float* op = (float*)&o;
        #pragma unroll
        for (int u = 0; u < 4; ++u) {
            const int k = kb*4 + u;
            float t = V[WS_B0 + k];
            t = fmaf(V[WS_A + k*4 + 0], qx, t);
            t = fmaf(V[WS_A + k*4 + 1], qy, t);
            t = fmaf(V[WS_A + k*4 + 2], qz, t);
            t = fmaf(V[WS_A + k*4 + 3], qw, t);
            op[u] = fmaf(t, inv, Bt[k]);
        }
        *(float4*)(slot + kb*4) = o;
    }
}

extern "C" void kernel_launch(void* const* d_in, const int* in_sizes, int n_in,
                              void* d_out, int out_size, void* d_ws, size_t ws_size,
                              hipStream_t stream) {
    const float* x     = (const float*)d_in[0];
    const float* wts   = (const float*)d_in[1];
    const float* W     = (const float*)d_in[2];
    const float* bias  = (const float*)d_in[3];
    const float* gamma = (const float*)d_in[4];
    const float* beta  = (const float*)d_in[5];
    float* out = (float*)d_out;
    float* ws  = (float*)d_ws;
    const int B = in_sizes[0] / 4;   // 262144

    hipLaunchKernelGGL(qb_setup, dim3(1),       dim3(64),  0, stream, wts, W, bias, gamma, ws);
    hipLaunchKernelGGL(qb_main,  dim3(B / 128), dim3(128), 0, stream, x, beta, ws, out);
}

// Round 9
// 93.451 us; speedup vs baseline: 1.1851x; 1.1851x over previous
//
#include <hip/hip_runtime.h>
#include <cstdint>

// ---------------------------------------------------------------------------
// QuantumBranch, R12: revert to R8 (best measured: 92.385us).
// R11 post-mortem (110.8us, regression): (1) exchange-free stores wrote 16B
// per lane at 256B stride = 64 distinct cache lines PER INSTRUCTION — a
// scatter, despite eventual full coverage; fill-style 6TB/s needs per-
// instruction contiguity (R8: 1KB contiguous per store instr). (2) i-outer
// matvec collapsed ILP to 2 dependent 16-FMA chains (vs 32 independent
// accumulators). Both hurt.
//
// Cross-session record (R3-R11): six structurally distinct mains (LDS-
// broadcast V, SGPR V, fused, split, scratch round-trip, scatter) all land
// main ~= 44+-4us; R8 counters show VALU 12%, HBM 18%, Occ 20%, LDS ~0 —
// no pipe loaded; per-CU issue work ~7us. The uniform 6x gap across
// structures is not counter-addressable at kernel level. Best total = R8.
// This restores R8 verbatim (absmax exactly 0.015625).
//
// Math (verified R1-R8): circuit collapses to V = U*diag((-i)^popc),
// z_w = sum_i +/- (r_i^2+s_i^2), r=Re(V)m, s=Im(V)m, m = product-state
// magnitudes from tanh(x)*pi/2. LayerNorm collapses to a 4x4 quadratic
// form: out[b,k] = inv_b*(A[k].q_b + B0[k]) + beta[k].
// ---------------------------------------------------------------------------

// block-shared LDS float offsets
#define WS_VRT 0     // 256: Re(V)^T  [col*16+row]
#define WS_VIT 256   // 256: Im(V)^T
#define WS_A   512   // 256: (W-colmean)*gamma  [k*4+w]
#define WS_B0  768   // 64:  (b-bmean)*gamma
#define WS_G   832   // 16:  G[4][4]
#define WS_g   848   // 4
#define WS_C0  852   // 1
#define WS_Q   864   // 2048: staged q (float4 x 512 samples)
#define WS_INV 2912  // 512:  staged inv
#define WREG   3424  // total floats (13696 B)

__global__ __launch_bounds__(256, 2) void qb_fused(const float* __restrict__ x,
                                                   const float* __restrict__ wts,
                                                   const float* __restrict__ W,
                                                   const float* __restrict__ bias,
                                                   const float* __restrict__ gamma,
                                                   const float* __restrict__ beta,
                                                   float* __restrict__ out) {
    __shared__ __align__(16) float wlds[WREG];
    const int tid  = threadIdx.x;
    const int wv   = tid >> 6;
    const int lane = tid & 63;

    // issue x loads first: HBM latency hides under pre-barrier compute.
    // thread owns local samples (wv*128+lane) and (wv*128+64+lane).
    const int base = blockIdx.x * 512 + wv * 128 + lane;
    const float4 xv0 = ((const float4*)x)[base];
    const float4 xv1 = ((const float4*)x)[base + 64];

    // beta for the store phase: independent of setup, issue before barrier
    const int k4t = lane & 15;
    const float4 Bt4v = ((const float4*)beta)[k4t];

    // ---- pre-barrier: product-state magnitudes for both samples ----
    float m0[16], m1[16];
    {
        const float xa[8] = {xv0.x, xv0.y, xv0.z, xv0.w,
                             xv1.x, xv1.y, xv1.z, xv1.w};
        float c4[8], s4[8];
        #pragma unroll
        for (int w = 0; w < 8; ++w) {
            const float h = tanhf(xa[w]) * 1.5707963267948966f;
            __sincosf(h, &s4[w], &c4[w]);
        }
        {
            const float e01[4] = {c4[0]*c4[1], c4[0]*s4[1], s4[0]*c4[1], s4[0]*s4[1]};
            const float e23[4] = {c4[2]*c4[3], c4[2]*s4[3], s4[2]*c4[3], s4[2]*s4[3]};
            #pragma unroll
            for (int j = 0; j < 16; ++j) m0[j] = e01[j>>2]*e23[j&3];
        }
        {
            const float e01[4] = {c4[4]*c4[5], c4[4]*s4[5], s4[4]*c4[5], s4[4]*s4[5]};
            const float e23[4] = {c4[6]*c4[7], c4[6]*s4[7], s4[6]*c4[7], s4[6]*s4[7]};
            #pragma unroll
            for (int j = 0; j < 16; ++j) m1[j] = e01[j>>2]*e23[j&3];
        }
    }

    // ---- wave 0: unitary -> V^T in block LDS ----
    if (wv == 0) {
        const int row = lane >> 2;
        const int cg  = lane & 3;
        float ur[4], ui[4];   // U[row][4cg+c]
        #pragma unroll
        for (int c = 0; c < 4; ++c) { ur[c] = (row == 4*cg + c) ? 1.f : 0.f; ui[c] = 0.f; }

        #pragma unroll
        for (int l = 0; l < 2; ++l) {
            #pragma unroll
            for (int w = 0; w < 4; ++w) {
                const float ph = wts[l*12 + w*3 + 0];
                const float th = wts[l*12 + w*3 + 1];
                const float om = wts[l*12 + w*3 + 2];
                float st, ct; __sincosf(0.5f*th, &st, &ct);
                float sp, cp; __sincosf(0.5f*(ph+om), &sp, &cp);
                float sm, cm; __sincosf(0.5f*(ph-om), &sm, &cm);
                const float a00r =  cp*ct, a00i = -sp*ct;
                const float a01r = -cm*st, a01i = -sm*st;
                const float a10r =  cm*st, a10i = -sm*st;
                const float a11r =  cp*ct, a11i =  sp*ct;
                const int m8 = 8 >> w;
                const int xm = m8 << 2;           // lane xor mask for row^m8
                const bool hi = (row & m8) != 0;
                #pragma unroll
                for (int c = 0; c < 4; ++c) {
                    const float pr = __shfl_xor(ur[c], xm, 64);
                    const float pi = __shfl_xor(ui[c], xm, 64);
                    float nr, ni;
                    if (!hi) {
                        nr = a00r*ur[c] - a00i*ui[c] + a01r*pr - a01i*pi;
                        ni = a00r*ui[c] + a00i*ur[c] + a01r*pi + a01i*pr;
                    } else {
                        nr = a11r*ur[c] - a11i*ui[c] + a10r*pr - a10i*pi;
                        ni = a11r*ui[c] + a11i*ur[c] + a10r*pi + a10i*pr;
                    }
                    ur[c] = nr; ui[c] = ni;
                }
            }
            const int rr = (l == 0) ? 1 : 2;
            #pragma unroll
            for (int w = 0; w < 4; ++w) {
                const int cmk = 8 >> w;
                const int tmk = 8 >> ((w + rr) & 3);
                const int src = (row & cmk) ? (row ^ tmk) : row;
                const int srcLane = src*4 + cg;
                #pragma unroll
                for (int c = 0; c < 4; ++c) {
                    ur[c] = __shfl(ur[c], srcLane, 64);
                    ui[c] = __shfl(ui[c], srcLane, 64);
                }
            }
        }

        // V = U * diag((-i)^popc(col)); park transposed in block LDS
        #pragma unroll
        for (int c = 0; c < 4; ++c) {
            const int col = 4*cg + c;
            const int p = __popc(col) & 3;
            float vr, vi;
            if (p == 0)      { vr =  ur[c]; vi =  ui[c]; }
            else if (p == 1) { vr =  ui[c]; vi = -ur[c]; }
            else if (p == 2) { vr = -ur[c]; vi = -ui[c]; }
            else             { vr = -ui[c]; vi =  ur[c]; }
            wlds[WS_VRT + col*16 + row] = vr;
            wlds[WS_VIT + col*16 + row] = vi;
        }
    } else if (wv == 1) {
        // ---- wave 1 (concurrent with wave 0): LN constants ----
        const int k = lane;
        const float4 wk = ((const float4*)W)[k];
        const float w0 = wk.x, w1 = wk.y, w2 = wk.z, w3 = wk.w;
        const float bk = bias[k];
        auto wsum = [](float v) {
            #pragma unroll
            for (int o = 32; o; o >>= 1) v += __shfl_xor(v, o, 64);
            return v;
        };
        const float inv64 = 1.f/64.f;
        const float mw0 = wsum(w0)*inv64, mw1 = wsum(w1)*inv64;
        const float mw2 = wsum(w2)*inv64, mw3 = wsum(w3)*inv64;
        const float bm = wsum(bk)*inv64;
        float cc[4] = {w0-mw0, w1-mw1, w2-mw2, w3-mw3};
        const float bc = bk - bm;
        const float gk = gamma[k];
        float4 av;
        av.x = cc[0]*gk; av.y = cc[1]*gk; av.z = cc[2]*gk; av.w = cc[3]*gk;
        ((float4*)(wlds + WS_A))[k] = av;
        wlds[WS_B0 + k] = bc*gk;
        // G is symmetric: 10 wave-sums instead of 16
        #pragma unroll
        for (int a = 0; a < 4; ++a)
            #pragma unroll
            for (int b2 = a; b2 < 4; ++b2) {
                const float s = wsum(cc[a]*cc[b2])*inv64;   // wave-uniform
                if (k == 0) {
                    wlds[WS_G + a*4 + b2] = s;
                    wlds[WS_G + b2*4 + a] = s;
                }
            }
        #pragma unroll
        for (int a = 0; a < 4; ++a) {
            const float s = wsum(bc*cc[a])*inv64;
            if (k == 0) wlds[WS_g + a] = s;
        }
        { const float s = wsum(bc*bc)*inv64; if (k == 0) wlds[WS_C0] = s; }
    }

    __syncthreads();   // the ONLY barrier: setup results now block-visible

    // store-phase constants (need the barrier for WS_A/WS_B0)
    float4 A4[4];
    #pragma unroll
    for (int u = 0; u < 4; ++u) A4[u] = ((const float4*)(wlds + WS_A))[k4t*4 + u];
    const float4 B04v = ((const float4*)(wlds + WS_B0))[k4t];
    const float B04[4] = {B04v.x, B04v.y, B04v.z, B04v.w};
    const float Bt4[4] = {Bt4v.x, Bt4v.y, Bt4v.z, Bt4v.w};

    const float4* vr4 = (const float4*)(wlds + WS_VRT);
    const float4* vi4 = (const float4*)(wlds + WS_VIT);

    // per-sample matvec: j-outer, FMA order identical to R6/R7
    auto matvec = [&](const float* m, float* r, float* si) {
        #pragma unroll
        for (int i = 0; i < 16; ++i) { r[i] = 0.f; si[i] = 0.f; }
        #pragma unroll
        for (int j = 0; j < 16; ++j) {
            const float mj = m[j];
            #pragma unroll
            for (int i4 = 0; i4 < 4; ++i4) {
                const float4 a = vr4[j*4 + i4];   // uniform-address broadcast
                const float4 b = vi4[j*4 + i4];
                r [i4*4+0] = fmaf(a.x, mj, r [i4*4+0]);
                r [i4*4+1] = fmaf(a.y, mj, r [i4*4+1]);
                r [i4*4+2] = fmaf(a.z, mj, r [i4*4+2]);
                r [i4*4+3] = fmaf(a.w, mj, r [i4*4+3]);
                si[i4*4+0] = fmaf(b.x, mj, si[i4*4+0]);
                si[i4*4+1] = fmaf(b.y, mj, si[i4*4+1]);
                si[i4*4+2] = fmaf(b.z, mj, si[i4*4+2]);
                si[i4*4+3] = fmaf(b.w, mj, si[i4*4+3]);
            }
        }
    };

    // finish (z -> softmax -> var -> inv), identical math per sample
    auto finish = [&](const float* r, const float* si, float4& qo, float& invo) {
        float z0 = 0.f, z1 = 0.f, z2 = 0.f, z3 = 0.f;
        #pragma unroll
        for (int i = 0; i < 16; ++i) {
            const float p = r[i]*r[i] + si[i]*si[i];
            z0 += (i & 8) ? -p : p;
            z1 += (i & 4) ? -p : p;
            z2 += (i & 2) ? -p : p;
            z3 += (i & 1) ? -p : p;
        }
        const float mx = fmaxf(fmaxf(z0, z1), fmaxf(z2, z3));
        const float e0 = __expf(z0-mx), e1 = __expf(z1-mx);
        const float e2 = __expf(z2-mx), e3 = __expf(z3-mx);
        const float rs = 1.f / (e0+e1+e2+e3);
        const float qx = e0*rs, qy = e1*rs, qz = e2*rs, qw = e3*rs;
        float var = wlds[WS_C0];
        {
            const float4 Gs0 = ((const float4*)(wlds + WS_G))[0];
            const float4 Gs1 = ((const float4*)(wlds + WS_G))[1];
            const float4 Gs2 = ((const float4*)(wlds + WS_G))[2];
            const float4 Gs3 = ((const float4*)(wlds + WS_G))[3];
            const float4 gv  = ((const float4*)(wlds + WS_g))[0];
            const float qa[4] = {qx, qy, qz, qw};
            const float4 Gs[4] = {Gs0, Gs1, Gs2, Gs3};
            const float ga[4] = {gv.x, gv.y, gv.z, gv.w};
            #pragma unroll
            for (int a = 0; a < 4; ++a) {
                float t = 2.f * ga[a];
                t = fmaf(Gs[a].x, qa[0], t);
                t = fmaf(Gs[a].y, qa[1], t);
                t = fmaf(Gs[a].z, qa[2], t);
                t = fmaf(Gs[a].w, qa[3], t);
                var = fmaf(qa[a], t, var);
            }
        }
        qo = make_float4(qx, qy, qz, qw);
        invo = rsqrtf(var + 1e-5f);
    };

    // 16 coalesced store iterations for one 64-sample half
    // (half h covers local samples [wv*128 + h*64, +64))
    float4* outv = (float4*)out + (size_t)blockIdx.x * 8192 + wv * 2048 + lane;
    auto store_half = [&](int h) {
        const float4* qld = (const float4*)(wlds + WS_Q) + wv*128 + h*64 + (lane >> 4);
        const float*  ild = wlds + WS_INV + wv*128 + h*64 + (lane >> 4);
        float4* ov = outv + h*1024;
        #pragma unroll
        for (int iter = 0; iter < 16; ++iter) {
            const float4 q  = qld[iter*4];     // 4 addrs/wave, conflict-free
            const float  iv = ild[iter*4];
            float4 o;
            float* op = (float*)&o;
            #pragma unroll
            for (int u = 0; u < 4; ++u) {
                float t = B04[u];
                t = fmaf(A4[u].x, q.x, t);
                t = fmaf(A4[u].y, q.y, t);
                t = fmaf(A4[u].z, q.z, t);
                t = fmaf(A4[u].w, q.w, t);
                op[u] = fmaf(t, iv, Bt4[u]);
            }
            ov[iter*64] = o;
        }
    };

    // ---- pipelined pass 0: sample 0 compute -> stage -> store ----
    {
        float r[16], t[16];
        matvec(m0, r, t);
        float4 q; float inv;
        finish(r, t, q, inv);
        // wave-local staging: same-wave RAW ordered by lgkmcnt, no barrier
        ((float4*)(wlds + WS_Q))[wv*128 + lane] = q;
        wlds[WS_INV + wv*128 + lane] = inv;
        store_half(0);
    }

    // ---- pipelined pass 1: sample 1 compute -> stage -> store ----
    {
        float r[16], t[16];
        matvec(m1, r, t);
        float4 q; float inv;
        finish(r, t, q, inv);
        ((float4*)(wlds + WS_Q))[wv*128 + 64 + lane] = q;
        wlds[WS_INV + wv*128 + 64 + lane] = inv;
        store_half(1);
    }
}

extern "C" void kernel_launch(void* const* d_in, const int* in_sizes, int n_in,
                              void* d_out, int out_size, void* d_ws, size_t ws_size,
                              hipStream_t stream) {
    const float* x     = (const float*)d_in[0];
    const float* wts   = (const float*)d_in[1];
    const float* W     = (const float*)d_in[2];
    const float* bias  = (const float*)d_in[3];
    const float* gamma = (const float*)d_in[4];
    const float* beta  = (const float*)d_in[5];
    float* out = (float*)d_out;
    const int B = in_sizes[0] / 4;   // 262144

    hipLaunchKernelGGL(qb_fused, dim3(B / 512), dim3(256), 0, stream,
                       x, wts, W, bias, gamma, beta, out);
}